// Round 7
// baseline (18.395 us; speedup 1.0000x reference)
//
#include <hip/hip_runtime.h>
#include <hip/hip_bf16.h>

// Problem constants (from reference)
#define NL 10            // node label alphabet
#define NE 4             // edge label alphabet
#define N1 79
#define PAD 10           // pad pseudo-label index
#define NLP 11           // NL + pad
#define NODE_INS_DEL 0.03f
#define SINK_ITERS 10

// ---------------------------------------------------------------------------
// Label-space GED (see round-5 derivation). This round: global prefetch into
// registers, h[bin][8] histogram layout (int4 B-reduce), stride-12 padded
// label-space matrices so C/D are ds_read_b128 dots. All float arithmetic
// orders identical to the verified round-6 kernel (pad terms are +0*0).
// ---------------------------------------------------------------------------
__global__ __launch_bounds__(512) void k_ged(
    const int* __restrict__ Ag1, const int* __restrict__ Ag2,
    const int* __restrict__ l1, const int* __restrict__ l2,
    const float* __restrict__ nw, const float* __restrict__ ew,
    float* __restrict__ dout)
{
    __shared__ float E_ext[121];        // exp(-0.5*cost) in label space
    __shared__ float Cc[121];           // node-cost in label space
    __shared__ float T5[25];            // edge-pair cost table
    __shared__ float Vm[121];           // V, [P*11+R] layout (for E)
    __shared__ __align__(16) float Vm12[132];    // V, stride-12 rows (pad=0)
    __shared__ int   lab1[N1], lab2[N1];
    __shared__ int   cnt1[NLP], cnt2[NLP];
    __shared__ __align__(16) int h1[605][8], h2[605][8];  // [bin][copy]
    __shared__ int   nd1[55], nd2[55];           // diagonal hists [a*11+P]
    __shared__ float M1f[605];
    __shared__ __align__(16) float M2f12[660];   // [b*132 + S*12 + T], pad=0
    __shared__ __align__(16) float UbT12[660];   // [b*132 + R*12 + S], pad=0
    __shared__ float N1f[55], N2f[55];
    __shared__ float rho[NLP], gam[NLP];
    __shared__ float Yb[605];
    __shared__ float redL[8];

    const int t = threadIdx.x;

    // ---------------- P: prefetch globals into registers ------------------
    int4 av[7];
    int diag1v = 0, diag2v = 0, tailv = 0, lv = 0;
    if (t >= 64 && t < 288) {
        const int q = t - 64;
        #pragma unroll
        for (int itr = 0; itr < 7; ++itr) {
            int m = q + itr * 224;
            av[itr] = (m < 1560) ? ((const int4*)Ag1)[m] : make_int4(0, 0, 0, 0);
        }
        if (t < 64 + N1) diag1v = Ag1[(t - 64) * 80];   // A1[j][j]
        if (t == 64)     tailv  = Ag1[6240];
    } else if (t >= 288) {
        const int q = t - 288;
        #pragma unroll
        for (int itr = 0; itr < 7; ++itr) {
            int m = q + itr * 224;
            av[itr] = (m < 1560) ? ((const int4*)Ag2)[m] : make_int4(0, 0, 0, 0);
        }
        if (t == 288) tailv = Ag2[6240];
    }
    if (t >= 144 && t < 144 + N1) diag2v = Ag2[(t - 144) * 80];  // A2[k][k]
    if (t < N1)              { lv = l1[t];      lab1[t] = lv; }
    if (t >= 79 && t < 158)  { lv = l2[t - 79]; lab2[t - 79] = lv; }

    // ---------------- A0: zero hists (int4), build tables -----------------
    {
        int4* hz1 = (int4*)&h1[0][0];   // 605*8 = 4840 ints = 1210 int4
        int4* hz2 = (int4*)&h2[0][0];
        const int4 z4 = make_int4(0, 0, 0, 0);
        for (int i = t; i < 1210; i += 512) { hz1[i] = z4; hz2[i] = z4; }
    }
    if (t < 55)  nd1[t] = 0;
    if (t >= 55 && t < 110) nd2[t - 55] = 0;
    if (t >= 158 && t < 168) cnt1[t - 158] = 0;
    if (t >= 168 && t < 178) cnt2[t - 168] = 0;
    if (t == 178) cnt1[PAD] = 1;
    if (t == 179) cnt2[PAD] = 1;
    if (t >= 192 && t < 313) {          // E_ext + Cc (label space, incl pad)
        int q = t - 192, P = q / 11, S = q - P * 11;
        float cost;
        if (P < NL && S < NL) {
            if (P == S) cost = 0.f;
            else {
                int x = min(P, S), y = max(P, S);
                int pidx = x * (NL - 1) - x * (x - 1) / 2 + (y - x - 1);
                cost = fmaxf(nw[pidx], 0.f);
            }
        } else if (P == PAD && S == PAD) cost = 0.f;
        else cost = NODE_INS_DEL;
        Cc[q] = cost;
        E_ext[q] = __expf(-0.5f * cost);
    }
    if (t >= 320 && t < 345) {          // edge table 5x5
        int q = t - 320, a = q / 5, b = q - a * 5;
        float val;
        if (a == 0 && b == 0)       val = 0.f;
        else if (a == 0 || b == 0)  val = fmaxf(ew[NE * (NE - 1) / 2], 0.f);
        else if (a == b)            val = 0.f;
        else {
            int x = min(a, b) - 1, y = max(a, b) - 1;
            int p = x * (NE - 1) - x * (x - 1) / 2 + (y - x - 1);
            val = fmaxf(ew[p], 0.f);
        }
        T5[q] = val;
    }
    __syncthreads();

    // ---------------- A1: label counts (from prefetched registers) --------
    if (t < N1)              atomicAdd(&cnt1[lv], 1);
    if (t >= 79 && t < 158)  atomicAdd(&cnt2[lv], 1);
    __syncthreads();

    // ---------------- A2: Sinkhorn (wave 0) || histograms (waves 1-7) ----
    if (t < 64) {
        const int X = t >> 2, q = t & 3;
        const bool valid = (X < NLP);
        float ec2[3], ec1[3];
        #pragma unroll
        for (int k = 0; k < 3; ++k) {
            int M = 3 * q + k;
            if (valid && M < NLP) {
                float e = E_ext[X * 11 + M];
                ec2[k] = e * (float)cnt2[M];
                ec1[k] = e * (float)cnt1[M];
            } else { ec2[k] = 0.f; ec1[k] = 0.f; }
        }
        const int s0 = 4 * (3 * q + 0);
        const int s1 = 4 * (3 * q + 1);
        const int s2 = (3 * q + 2 < NLP) ? 4 * (3 * q + 2) : 0;
        float gX = 1.0f, rX = 1.0f;
        for (int it = 0; it < SINK_ITERS; ++it) {
            float g0 = __shfl(gX, s0, 64);
            float g1 = __shfl(gX, s1, 64);
            float g2 = __shfl(gX, s2, 64);
            float y = ec2[0] * g0 + ec2[1] * g1 + ec2[2] * g2;
            y += __shfl_xor(y, 1, 64);
            y += __shfl_xor(y, 2, 64);
            rX = valid ? (1.0f / y) : 0.f;
            float r0 = __shfl(rX, s0, 64);
            float r1 = __shfl(rX, s1, 64);
            float r2 = __shfl(rX, s2, 64);
            float z = ec1[0] * r0 + ec1[1] * r1 + ec1[2] * r2;
            z += __shfl_xor(z, 1, 64);
            z += __shfl_xor(z, 2, 64);
            gX = valid ? (1.0f / z) : 0.f;
        }
        if (valid && q == 0) { rho[X] = rX; gam[X] = gX; }
    } else if (t < 288) {
        const int cp = t & 7;
        // pad borders (i=79 row / j=79 col of the padded 80x80):
        if (t >= 64 && t < 75)   atomicAdd(&h1[(t - 64) * 11 + 10][1], cnt1[t - 64]);
        if (t >= 80 && t < 90)   atomicAdd(&h1[110 + (t - 80)][1], cnt1[t - 80]);
        if (t >= 96 && t < 107)  atomicAdd(&h2[(t - 96) * 11 + 10][1], cnt2[t - 96]);
        if (t >= 112 && t < 122) atomicAdd(&h2[110 + (t - 112)][1], cnt2[t - 112]);
        // diagonal histograms (prefetched)
        if (t >= 64 && t < 64 + N1)  atomicAdd(&nd1[diag1v * 11 + lab1[t - 64]], 1);
        if (t >= 144 && t < 144 + N1) atomicAdd(&nd2[diag2v * 11 + lab2[t - 144]], 1);
        if (t == 224) nd1[10] = 1;   // pad diag: a=0, P=PAD
        if (t == 225) nd2[10] = 1;
        // interior stream from prefetched registers
        const int q = t - 64;
        #pragma unroll
        for (int itr = 0; itr < 7; ++itr) {
            int m = q + itr * 224;
            if (m < 1560) {
                int4 a4 = av[itr];
                int n0 = 4 * m;
                { int n = n0 + 0, i = n / 79, jj = n - i * 79;
                  atomicAdd(&h1[a4.x * 121 + lab1[jj] * 11 + lab1[i]][cp], 1); }
                { int n = n0 + 1, i = n / 79, jj = n - i * 79;
                  atomicAdd(&h1[a4.y * 121 + lab1[jj] * 11 + lab1[i]][cp], 1); }
                { int n = n0 + 2, i = n / 79, jj = n - i * 79;
                  atomicAdd(&h1[a4.z * 121 + lab1[jj] * 11 + lab1[i]][cp], 1); }
                { int n = n0 + 3, i = n / 79, jj = n - i * 79;
                  atomicAdd(&h1[a4.w * 121 + lab1[jj] * 11 + lab1[i]][cp], 1); }
            }
        }
        if (t == 64)   // tail element n=6240 -> i=j=78
            atomicAdd(&h1[tailv * 121 + lab1[78] * 11 + lab1[78]][cp], 1);
    } else {
        const int cp = t & 7;
        const int q = t - 288;
        #pragma unroll
        for (int itr = 0; itr < 7; ++itr) {
            int m = q + itr * 224;
            if (m < 1560) {
                int4 a4 = av[itr];
                int n0 = 4 * m;
                { int n = n0 + 0, k = n / 79, ll = n - k * 79;
                  atomicAdd(&h2[a4.x * 121 + lab2[k] * 11 + lab2[ll]][cp], 1); }
                { int n = n0 + 1, k = n / 79, ll = n - k * 79;
                  atomicAdd(&h2[a4.y * 121 + lab2[k] * 11 + lab2[ll]][cp], 1); }
                { int n = n0 + 2, k = n / 79, ll = n - k * 79;
                  atomicAdd(&h2[a4.z * 121 + lab2[k] * 11 + lab2[ll]][cp], 1); }
                { int n = n0 + 3, k = n / 79, ll = n - k * 79;
                  atomicAdd(&h2[a4.w * 121 + lab2[k] * 11 + lab2[ll]][cp], 1); }
            }
        }
        if (t == 288)  // tail element n=6240 -> k=l=78
            atomicAdd(&h2[tailv * 121 + lab2[78] * 11 + lab2[78]][cp], 1);
    }
    __syncthreads();

    // ---------------- B: int4 reduce hist copies; build V; zero pads ------
    for (int i = t; i < 605; i += 512) {
        const int4* p1 = (const int4*)&h1[i][0];
        int4 x0 = p1[0], x1 = p1[1];
        int s1v = x0.x + x0.y + x0.z + x0.w + x1.x + x1.y + x1.z + x1.w;
        M1f[i] = (float)s1v;
        const int4* p2 = (const int4*)&h2[i][0];
        int4 y0 = p2[0], y1 = p2[1];
        int s2v = y0.x + y0.y + y0.z + y0.w + y1.x + y1.y + y1.z + y1.w;
        int b = i / 121, r = i - b * 121, S = r / 11, T = r - S * 11;
        M2f12[b * 132 + S * 12 + T] = (float)s2v;
    }
    if (t < 55) N1f[t] = (float)nd1[t];
    if (t >= 55 && t < 110) N2f[t - 55] = (float)nd2[t - 55];
    if (t >= 64 && t < 185) {
        int q = t - 64, P = q / 11, R = q - P * 11;
        float val = rho[P] * E_ext[q] * gam[R];
        Vm[q] = val;
        Vm12[P * 12 + R] = val;
    }
    // zero pads (col 11 of every stride-12 row)
    if (t >= 256 && t < 311) { int q = t - 256; M2f12[(q / 11) * 132 + (q % 11) * 12 + 11] = 0.f; }
    if (t >= 311 && t < 366) { int q = t - 311; UbT12[(q / 11) * 132 + (q % 11) * 12 + 11] = 0.f; }
    if (t >= 366 && t < 377) { Vm12[(t - 366) * 12 + 11] = 0.f; }
    __syncthreads();

    // ---------------- C: UbT[b][R][S] = sum_T M2[b][S][T] * V[R][T] -------
    for (int idx = t; idx < 605; idx += 512) {
        int b = idx / 121, r = idx - b * 121;
        int S = r / 11, R = r - S * 11;
        const float4* m2 = (const float4*)&M2f12[b * 132 + S * 12];
        const float4* vr = (const float4*)&Vm12[R * 12];
        float4 m0 = m2[0], m1 = m2[1], m2v = m2[2];
        float4 v0 = vr[0], v1 = vr[1], v2 = vr[2];
        float s = 0.f;
        s = fmaf(m0.x, v0.x, s); s = fmaf(m0.y, v0.y, s);
        s = fmaf(m0.z, v0.z, s); s = fmaf(m0.w, v0.w, s);
        s = fmaf(m1.x, v1.x, s); s = fmaf(m1.y, v1.y, s);
        s = fmaf(m1.z, v1.z, s); s = fmaf(m1.w, v1.w, s);
        s = fmaf(m2v.x, v2.x, s); s = fmaf(m2v.y, v2.y, s);
        s = fmaf(m2v.z, v2.z, s); s = fmaf(m2v.w, v2.w, s);   // pad: +0*0
        UbT12[b * 132 + R * 12 + S] = s;
    }
    __syncthreads();

    // ---------------- D: Yb[b][P][R] = sum_S V[P][S] * UbT[b][R][S] -------
    for (int idx = t; idx < 605; idx += 512) {
        int b = idx / 121, r = idx - b * 121;
        int P = r / 11, R = r - P * 11;
        const float4* vp = (const float4*)&Vm12[P * 12];
        const float4* up = (const float4*)&UbT12[b * 132 + R * 12];
        float4 a0 = vp[0], a1 = vp[1], a2 = vp[2];
        float4 b0 = up[0], b1 = up[1], b2 = up[2];
        float s = 0.f;
        s = fmaf(a0.x, b0.x, s); s = fmaf(a0.y, b0.y, s);
        s = fmaf(a0.z, b0.z, s); s = fmaf(a0.w, b0.w, s);
        s = fmaf(a1.x, b1.x, s); s = fmaf(a1.y, b1.y, s);
        s = fmaf(a1.z, b1.z, s); s = fmaf(a1.w, b1.w, s);
        s = fmaf(a2.x, b2.x, s); s = fmaf(a2.y, b2.y, s);
        s = fmaf(a2.z, b2.z, s); s = fmaf(a2.w, b2.w, s);     // pad: +0*0
        Yb[idx] = s;
    }
    __syncthreads();

    // ---------------- E: final contraction + reduce ----------------------
    float part = 0.f;
    if (t < 121) {
        int P = t / 11, R = t - P * 11;
        float qf = 0.f;
        #pragma unroll
        for (int a = 0; a < 5; ++a) {
            float sa = 0.f;
            #pragma unroll
            for (int b = 0; b < 5; ++b) sa = fmaf(T5[a * 5 + b], Yb[b * 121 + t], sa);
            qf = fmaf(M1f[a * 121 + t], sa, qf);
        }
        float sd = 0.f;
        #pragma unroll
        for (int a = 0; a < 5; ++a) {
            float sb = 0.f;
            #pragma unroll
            for (int b = 0; b < 5; ++b) sb = fmaf(T5[a * 5 + b], N2f[b * 11 + R], sb);
            sd = fmaf(N1f[a * 11 + P], sb, sd);
        }
        float vv = Vm[t];
        float dpart = vv * vv * sd;
        float cvp = (float)cnt1[P] * (float)cnt2[R] * Cc[t] * vv;
        part = cvp + 0.5f * (qf - dpart);
    }
    #pragma unroll
    for (int off = 1; off < 64; off <<= 1) part += __shfl_xor(part, off, 64);
    if ((t & 63) == 0) redL[t >> 6] = part;
    __syncthreads();
    if (t == 0) {
        float s = 0.f;
        #pragma unroll
        for (int w = 0; w < 8; ++w) s += redL[w];
        dout[0] = s;
    }
}

extern "C" void kernel_launch(void* const* d_in, const int* in_sizes, int n_in,
                              void* d_out, int out_size, void* d_ws, size_t ws_size,
                              hipStream_t stream) {
    const int*   Ag1 = (const int*)d_in[0];
    const int*   Ag2 = (const int*)d_in[1];
    const int*   l1  = (const int*)d_in[2];
    const int*   l2  = (const int*)d_in[3];
    const float* nw  = (const float*)d_in[4];
    const float* ew  = (const float*)d_in[5];
    float* out = (float*)d_out;

    k_ged<<<1, 512, 0, stream>>>(Ag1, Ag2, l1, l2, nw, ew, out);
}

// Round 8
// 13.176 us; speedup vs baseline: 1.3961x; 1.3961x over previous
//
#include <hip/hip_runtime.h>
#include <hip/hip_bf16.h>

// Problem constants (from reference)
#define NL 10            // node label alphabet
#define NE 4             // edge label alphabet
#define N1 79
#define PAD 10           // pad pseudo-label index
#define NLP 11           // NL + pad
#define NODE_INS_DEL 0.03f
#define SINK_ITERS 10

// ---------------------------------------------------------------------------
// Label-space GED (round-5 derivation; round-6 layout, which measured 12.66us.
// Round-7's three-way bundle regressed to 18.4us and is reverted).
// Only delta vs round 6: within-branch hoist of the 7 int4 adjacency loads
// ahead of the atomic loop (short register live range, no layout changes).
// ---------------------------------------------------------------------------
__global__ __launch_bounds__(512) void k_ged(
    const int* __restrict__ Ag1, const int* __restrict__ Ag2,
    const int* __restrict__ l1, const int* __restrict__ l2,
    const float* __restrict__ nw, const float* __restrict__ ew,
    float* __restrict__ dout)
{
    __shared__ float E_ext[121];        // exp(-0.5*cost) in label space (symmetric)
    __shared__ float Cc[121];           // node-cost in label space (with pad borders)
    __shared__ float T5[25];            // edge-pair cost table
    __shared__ float Vm[121];           // V = diag(rho) E_ext diag(gam)
    __shared__ int   lab1[N1], lab2[N1];
    __shared__ int   cnt1[NLP], cnt2[NLP];
    __shared__ __align__(16) int h1[8][605], h2[8][605];   // privatized histograms
    __shared__ int   nd1[55], nd2[55];         // diagonal histograms [a][P]
    __shared__ float M1f[605], M2f[605];
    __shared__ float N1f[55], N2f[55];
    __shared__ float rho[NLP], gam[NLP];
    __shared__ float Ub[605], Yb[605];
    __shared__ float redL[8];

    const int t = threadIdx.x;

    // ---------------- A0: zero (int4), load labels, build tables ----------
    {
        int4* hz1 = (int4*)&h1[0][0];   // 8*605 = 4840 ints = 1210 int4
        int4* hz2 = (int4*)&h2[0][0];
        const int4 z4 = make_int4(0, 0, 0, 0);
        for (int i = t; i < 1210; i += 512) { hz1[i] = z4; hz2[i] = z4; }
    }
    if (t < 55)  nd1[t] = 0;
    if (t >= 55 && t < 110) nd2[t - 55] = 0;
    if (t >= 158 && t < 168) cnt1[t - 158] = 0;
    if (t >= 168 && t < 178) cnt2[t - 168] = 0;
    if (t == 178) cnt1[PAD] = 1;
    if (t == 179) cnt2[PAD] = 1;
    if (t < N1)               lab1[t] = l1[t];
    if (t >= 79 && t < 158)   lab2[t - 79] = l2[t - 79];
    if (t >= 192 && t < 313) {          // E_ext + Cc (label space, incl pad)
        int q = t - 192, P = q / 11, S = q - P * 11;
        float cost;
        if (P < NL && S < NL) {
            if (P == S) cost = 0.f;
            else {
                int x = min(P, S), y = max(P, S);
                int pidx = x * (NL - 1) - x * (x - 1) / 2 + (y - x - 1);
                cost = fmaxf(nw[pidx], 0.f);
            }
        } else if (P == PAD && S == PAD) cost = 0.f;
        else cost = NODE_INS_DEL;
        Cc[q] = cost;
        E_ext[q] = __expf(-0.5f * cost);
    }
    if (t >= 320 && t < 345) {          // edge table 5x5
        int q = t - 320, a = q / 5, b = q - a * 5;
        float val;
        if (a == 0 && b == 0)       val = 0.f;
        else if (a == 0 || b == 0)  val = fmaxf(ew[NE * (NE - 1) / 2], 0.f);
        else if (a == b)            val = 0.f;
        else {
            int x = min(a, b) - 1, y = max(a, b) - 1;
            int p = x * (NE - 1) - x * (x - 1) / 2 + (y - x - 1);
            val = fmaxf(ew[p], 0.f);
        }
        T5[q] = val;
    }
    __syncthreads();

    // ---------------- A1: label counts ----------------
    if (t < N1)               atomicAdd(&cnt1[lab1[t]], 1);
    if (t >= 79 && t < 158)   atomicAdd(&cnt2[lab2[t - 79]], 1);
    __syncthreads();

    // ---------------- A2: Sinkhorn (wave 0) || histograms (waves 1-7) ----
    if (t < 64) {
        // Label-space Sinkhorn: lane = X*4+q; group of 4 lanes computes the
        // 11-term dot for label X (3 terms per lane), xor-reduced in-group.
        const int X = t >> 2, q = t & 3;
        const bool valid = (X < NLP);
        float ec2[3], ec1[3];
        #pragma unroll
        for (int k = 0; k < 3; ++k) {
            int M = 3 * q + k;
            if (valid && M < NLP) {
                float e = E_ext[X * 11 + M];
                ec2[k] = e * (float)cnt2[M];
                ec1[k] = e * (float)cnt1[M];
            } else { ec2[k] = 0.f; ec1[k] = 0.f; }
        }
        const int s0 = 4 * (3 * q + 0);
        const int s1 = 4 * (3 * q + 1);
        const int s2 = (3 * q + 2 < NLP) ? 4 * (3 * q + 2) : 0;  // clamp: weight is 0
        float gX = 1.0f, rX = 1.0f;
        for (int it = 0; it < SINK_ITERS; ++it) {
            float g0 = __shfl(gX, s0, 64);
            float g1 = __shfl(gX, s1, 64);
            float g2 = __shfl(gX, s2, 64);
            float y = ec2[0] * g0 + ec2[1] * g1 + ec2[2] * g2;
            y += __shfl_xor(y, 1, 64);
            y += __shfl_xor(y, 2, 64);
            rX = valid ? (1.0f / y) : 0.f;
            float r0 = __shfl(rX, s0, 64);
            float r1 = __shfl(rX, s1, 64);
            float r2 = __shfl(rX, s2, 64);
            float z = ec1[0] * r0 + ec1[1] * r1 + ec1[2] * r2;
            z += __shfl_xor(z, 1, 64);
            z += __shfl_xor(z, 2, 64);
            gX = valid ? (1.0f / z) : 0.f;
        }
        if (valid && q == 0) { rho[X] = rX; gam[X] = gX; }
    } else if (t < 288) {
        // graph-1 interior histogram: M1[a][lab1[j]][lab1[i]]
        int* hp = h1[t & 7];
        // hoist the 7 int4 loads ahead of the atomic chain (within-branch)
        const int q = t - 64;
        int4 av[7];
        #pragma unroll
        for (int itr = 0; itr < 7; ++itr) {
            int m = q + itr * 224;
            av[itr] = (m < 1560) ? ((const int4*)Ag1)[m] : make_int4(0, 0, 0, 0);
        }
        // pad borders (i=79 row / j=79 col of the padded 80x80):
        if (t >= 64 && t < 75)   atomicAdd(&h1[1][(t - 64) * 11 + 10], cnt1[t - 64]);
        if (t >= 80 && t < 90)   atomicAdd(&h1[1][110 + (t - 80)], cnt1[t - 80]);
        if (t >= 96 && t < 107)  atomicAdd(&h2[1][(t - 96) * 11 + 10], cnt2[t - 96]);
        if (t >= 112 && t < 122) atomicAdd(&h2[1][110 + (t - 112)], cnt2[t - 112]);
        // diagonal histograms
        if (t >= 64 && t < 64 + N1) {
            int j = t - 64;
            atomicAdd(&nd1[Ag1[j * 80] * 11 + lab1[j]], 1);   // A1[j][j]
        }
        if (t >= 144 && t < 144 + N1) {
            int k = t - 144;
            atomicAdd(&nd2[Ag2[k * 80] * 11 + lab2[k]], 1);
        }
        if (t == 224) nd1[10] = 1;   // pad diag: a=0, P=PAD
        if (t == 225) nd2[10] = 1;
        // interior stream from the hoisted registers
        #pragma unroll
        for (int itr = 0; itr < 7; ++itr) {
            int m = q + itr * 224;
            if (m < 1560) {
                int4 a4 = av[itr];
                int n0 = 4 * m;
                { int n = n0 + 0, i = n / 79, jj = n - i * 79;
                  atomicAdd(&hp[a4.x * 121 + lab1[jj] * 11 + lab1[i]], 1); }
                { int n = n0 + 1, i = n / 79, jj = n - i * 79;
                  atomicAdd(&hp[a4.y * 121 + lab1[jj] * 11 + lab1[i]], 1); }
                { int n = n0 + 2, i = n / 79, jj = n - i * 79;
                  atomicAdd(&hp[a4.z * 121 + lab1[jj] * 11 + lab1[i]], 1); }
                { int n = n0 + 3, i = n / 79, jj = n - i * 79;
                  atomicAdd(&hp[a4.w * 121 + lab1[jj] * 11 + lab1[i]], 1); }
            }
        }
        if (t == 64) {   // tail element n=6240 -> i=j=78
            int a = Ag1[6240];
            atomicAdd(&hp[a * 121 + lab1[78] * 11 + lab1[78]], 1);
        }
    } else {
        // graph-2 interior histogram: M2[b][lab2[k]][lab2[l]]
        int* hp = h2[t & 7];
        const int q = t - 288;
        int4 av[7];
        #pragma unroll
        for (int itr = 0; itr < 7; ++itr) {
            int m = q + itr * 224;
            av[itr] = (m < 1560) ? ((const int4*)Ag2)[m] : make_int4(0, 0, 0, 0);
        }
        #pragma unroll
        for (int itr = 0; itr < 7; ++itr) {
            int m = q + itr * 224;
            if (m < 1560) {
                int4 a4 = av[itr];
                int n0 = 4 * m;
                { int n = n0 + 0, k = n / 79, ll = n - k * 79;
                  atomicAdd(&hp[a4.x * 121 + lab2[k] * 11 + lab2[ll]], 1); }
                { int n = n0 + 1, k = n / 79, ll = n - k * 79;
                  atomicAdd(&hp[a4.y * 121 + lab2[k] * 11 + lab2[ll]], 1); }
                { int n = n0 + 2, k = n / 79, ll = n - k * 79;
                  atomicAdd(&hp[a4.z * 121 + lab2[k] * 11 + lab2[ll]], 1); }
                { int n = n0 + 3, k = n / 79, ll = n - k * 79;
                  atomicAdd(&hp[a4.w * 121 + lab2[k] * 11 + lab2[ll]], 1); }
            }
        }
        if (t == 288) {  // tail element n=6240 -> k=l=78
            int b = Ag2[6240];
            atomicAdd(&hp[b * 121 + lab2[78] * 11 + lab2[78]], 1);
        }
    }
    __syncthreads();

    // ---------------- B: reduce histogram copies; build V ----------------
    for (int i = t; i < 605; i += 512) {
        int s1v = 0, s2v = 0;
        #pragma unroll
        for (int w = 0; w < 8; ++w) { s1v += h1[w][i]; s2v += h2[w][i]; }
        M1f[i] = (float)s1v;
        M2f[i] = (float)s2v;
    }
    if (t < 55) { N1f[t] = (float)nd1[t]; N2f[t] = (float)nd2[t]; }
    if (t >= 64 && t < 185) {
        int q = t - 64;
        Vm[q] = rho[q / 11] * E_ext[q] * gam[q % 11];
    }
    __syncthreads();

    // ---------------- C: Ub[b][S][R] = sum_T M2[b][S][T] * V[R][T] -------
    for (int idx = t; idx < 605; idx += 512) {
        int b = idx / 121, r = idx - b * 121;
        int S = r / 11, R = r - S * 11;
        const float* m2 = &M2f[b * 121 + S * 11];
        const float* vr = &Vm[R * 11];
        float s = 0.f;
        #pragma unroll
        for (int T = 0; T < 11; ++T) s = fmaf(m2[T], vr[T], s);
        Ub[idx] = s;
    }
    __syncthreads();

    // ---------------- D: Yb[b][P][R] = sum_S V[P][S] * Ub[b][S][R] -------
    for (int idx = t; idx < 605; idx += 512) {
        int b = idx / 121, r = idx - b * 121;
        int P = r / 11, R = r - P * 11;
        float s = 0.f;
        #pragma unroll
        for (int S = 0; S < 11; ++S) s = fmaf(Vm[P * 11 + S], Ub[b * 121 + S * 11 + R], s);
        Yb[idx] = s;
    }
    __syncthreads();

    // ---------------- E: final contraction + reduce ----------------------
    float part = 0.f;
    if (t < 121) {
        int P = t / 11, R = t - P * 11;
        float qf = 0.f;
        #pragma unroll
        for (int a = 0; a < 5; ++a) {
            float sa = 0.f;
            #pragma unroll
            for (int b = 0; b < 5; ++b) sa = fmaf(T5[a * 5 + b], Yb[b * 121 + t], sa);
            qf = fmaf(M1f[a * 121 + t], sa, qf);
        }
        float sd = 0.f;
        #pragma unroll
        for (int a = 0; a < 5; ++a) {
            float sb = 0.f;
            #pragma unroll
            for (int b = 0; b < 5; ++b) sb = fmaf(T5[a * 5 + b], N2f[b * 11 + R], sb);
            sd = fmaf(N1f[a * 11 + P], sb, sd);
        }
        float vv = Vm[t];
        float dpart = vv * vv * sd;
        float cvp = (float)cnt1[P] * (float)cnt2[R] * Cc[t] * vv;
        part = cvp + 0.5f * (qf - dpart);
    }
    #pragma unroll
    for (int off = 1; off < 64; off <<= 1) part += __shfl_xor(part, off, 64);
    if ((t & 63) == 0) redL[t >> 6] = part;
    __syncthreads();
    if (t == 0) {
        float s = 0.f;
        #pragma unroll
        for (int w = 0; w < 8; ++w) s += redL[w];
        dout[0] = s;
    }
}

extern "C" void kernel_launch(void* const* d_in, const int* in_sizes, int n_in,
                              void* d_out, int out_size, void* d_ws, size_t ws_size,
                              hipStream_t stream) {
    const int*   Ag1 = (const int*)d_in[0];
    const int*   Ag2 = (const int*)d_in[1];
    const int*   l1  = (const int*)d_in[2];
    const int*   l2  = (const int*)d_in[3];
    const float* nw  = (const float*)d_in[4];
    const float* ew  = (const float*)d_in[5];
    float* out = (float*)d_out;

    k_ged<<<1, 512, 0, stream>>>(Ag1, Ag2, l1, l2, nw, ew, out);
}

// Round 9
// 11.826 us; speedup vs baseline: 1.5554x; 1.1141x over previous
//
#include <hip/hip_runtime.h>
#include <hip/hip_bf16.h>

// Problem constants (from reference)
#define NL 10            // node label alphabet
#define NE 4             // edge label alphabet
#define N1 79
#define PAD 10           // pad pseudo-label index
#define NLP 11           // NL + pad
#define NODE_INS_DEL 0.03f
#define SINK_ITERS 10

// ---------------------------------------------------------------------------
// Label-space GED (round-5 derivation; round-6 layout = best measured 12.66us).
// Only delta vs round 6: histogram branch split is WAVE-ALIGNED (t<320), so
// no wave executes both atomic chains (round 6's wave 4 straddled t=288 and
// serially ran both 28-iter chains). g1: 256 workers x 7 iters stride 256;
// g2: 192 workers x 9 iters stride 192. All arithmetic identical to round 6.
// ---------------------------------------------------------------------------
__global__ __launch_bounds__(512) void k_ged(
    const int* __restrict__ Ag1, const int* __restrict__ Ag2,
    const int* __restrict__ l1, const int* __restrict__ l2,
    const float* __restrict__ nw, const float* __restrict__ ew,
    float* __restrict__ dout)
{
    __shared__ float E_ext[121];        // exp(-0.5*cost) in label space (symmetric)
    __shared__ float Cc[121];           // node-cost in label space (with pad borders)
    __shared__ float T5[25];            // edge-pair cost table
    __shared__ float Vm[121];           // V = diag(rho) E_ext diag(gam)
    __shared__ int   lab1[N1], lab2[N1];
    __shared__ int   cnt1[NLP], cnt2[NLP];
    __shared__ __align__(16) int h1[8][605], h2[8][605];   // privatized histograms
    __shared__ int   nd1[55], nd2[55];         // diagonal histograms [a][P]
    __shared__ float M1f[605], M2f[605];
    __shared__ float N1f[55], N2f[55];
    __shared__ float rho[NLP], gam[NLP];
    __shared__ float Ub[605], Yb[605];
    __shared__ float redL[8];

    const int t = threadIdx.x;

    // ---------------- A0: zero (int4), load labels, build tables ----------
    {
        int4* hz1 = (int4*)&h1[0][0];   // 8*605 = 4840 ints = 1210 int4
        int4* hz2 = (int4*)&h2[0][0];
        const int4 z4 = make_int4(0, 0, 0, 0);
        for (int i = t; i < 1210; i += 512) { hz1[i] = z4; hz2[i] = z4; }
    }
    if (t < 55)  nd1[t] = 0;
    if (t >= 55 && t < 110) nd2[t - 55] = 0;
    if (t >= 158 && t < 168) cnt1[t - 158] = 0;
    if (t >= 168 && t < 178) cnt2[t - 168] = 0;
    if (t == 178) cnt1[PAD] = 1;
    if (t == 179) cnt2[PAD] = 1;
    if (t < N1)               lab1[t] = l1[t];
    if (t >= 79 && t < 158)   lab2[t - 79] = l2[t - 79];
    if (t >= 192 && t < 313) {          // E_ext + Cc (label space, incl pad)
        int q = t - 192, P = q / 11, S = q - P * 11;
        float cost;
        if (P < NL && S < NL) {
            if (P == S) cost = 0.f;
            else {
                int x = min(P, S), y = max(P, S);
                int pidx = x * (NL - 1) - x * (x - 1) / 2 + (y - x - 1);
                cost = fmaxf(nw[pidx], 0.f);
            }
        } else if (P == PAD && S == PAD) cost = 0.f;
        else cost = NODE_INS_DEL;
        Cc[q] = cost;
        E_ext[q] = __expf(-0.5f * cost);
    }
    if (t >= 320 && t < 345) {          // edge table 5x5
        int q = t - 320, a = q / 5, b = q - a * 5;
        float val;
        if (a == 0 && b == 0)       val = 0.f;
        else if (a == 0 || b == 0)  val = fmaxf(ew[NE * (NE - 1) / 2], 0.f);
        else if (a == b)            val = 0.f;
        else {
            int x = min(a, b) - 1, y = max(a, b) - 1;
            int p = x * (NE - 1) - x * (x - 1) / 2 + (y - x - 1);
            val = fmaxf(ew[p], 0.f);
        }
        T5[q] = val;
    }
    __syncthreads();

    // ---------------- A1: label counts ----------------
    if (t < N1)               atomicAdd(&cnt1[lab1[t]], 1);
    if (t >= 79 && t < 158)   atomicAdd(&cnt2[lab2[t - 79]], 1);
    __syncthreads();

    // ---------------- A2: Sinkhorn (wave 0) || histograms (waves 1-7) ----
    if (t < 64) {
        // Label-space Sinkhorn: lane = X*4+q; group of 4 lanes computes the
        // 11-term dot for label X (3 terms per lane), xor-reduced in-group.
        const int X = t >> 2, q = t & 3;
        const bool valid = (X < NLP);
        float ec2[3], ec1[3];
        #pragma unroll
        for (int k = 0; k < 3; ++k) {
            int M = 3 * q + k;
            if (valid && M < NLP) {
                float e = E_ext[X * 11 + M];
                ec2[k] = e * (float)cnt2[M];
                ec1[k] = e * (float)cnt1[M];
            } else { ec2[k] = 0.f; ec1[k] = 0.f; }
        }
        const int s0 = 4 * (3 * q + 0);
        const int s1 = 4 * (3 * q + 1);
        const int s2 = (3 * q + 2 < NLP) ? 4 * (3 * q + 2) : 0;  // clamp: weight is 0
        float gX = 1.0f, rX = 1.0f;
        for (int it = 0; it < SINK_ITERS; ++it) {
            float g0 = __shfl(gX, s0, 64);
            float g1 = __shfl(gX, s1, 64);
            float g2 = __shfl(gX, s2, 64);
            float y = ec2[0] * g0 + ec2[1] * g1 + ec2[2] * g2;
            y += __shfl_xor(y, 1, 64);
            y += __shfl_xor(y, 2, 64);
            rX = valid ? (1.0f / y) : 0.f;
            float r0 = __shfl(rX, s0, 64);
            float r1 = __shfl(rX, s1, 64);
            float r2 = __shfl(rX, s2, 64);
            float z = ec1[0] * r0 + ec1[1] * r1 + ec1[2] * r2;
            z += __shfl_xor(z, 1, 64);
            z += __shfl_xor(z, 2, 64);
            gX = valid ? (1.0f / z) : 0.f;
        }
        if (valid && q == 0) { rho[X] = rX; gam[X] = gX; }
    } else if (t < 320) {
        // graph-1 interior histogram: M1[a][lab1[j]][lab1[i]]  (waves 1-4)
        int* hp = h1[t & 7];
        // pad borders (i=79 row / j=79 col of the padded 80x80):
        if (t >= 64 && t < 75)   atomicAdd(&h1[1][(t - 64) * 11 + 10], cnt1[t - 64]);
        if (t >= 80 && t < 90)   atomicAdd(&h1[1][110 + (t - 80)], cnt1[t - 80]);
        if (t >= 96 && t < 107)  atomicAdd(&h2[1][(t - 96) * 11 + 10], cnt2[t - 96]);
        if (t >= 112 && t < 122) atomicAdd(&h2[1][110 + (t - 112)], cnt2[t - 112]);
        // diagonal histograms
        if (t >= 64 && t < 64 + N1) {
            int j = t - 64;
            atomicAdd(&nd1[Ag1[j * 80] * 11 + lab1[j]], 1);   // A1[j][j]
        }
        if (t >= 144 && t < 144 + N1) {
            int k = t - 144;
            atomicAdd(&nd2[Ag2[k * 80] * 11 + lab2[k]], 1);
        }
        if (t == 224) nd1[10] = 1;   // pad diag: a=0, P=PAD
        if (t == 225) nd2[10] = 1;
        // interior stream, int4-vectorized: 256 workers x 7 iters stride 256
        const int q = t - 64;
        #pragma unroll
        for (int itr = 0; itr < 7; ++itr) {
            int m = q + itr * 256;
            if (m < 1560) {
                int4 a4 = ((const int4*)Ag1)[m];
                int n0 = 4 * m;
                { int n = n0 + 0, i = n / 79, jj = n - i * 79;
                  atomicAdd(&hp[a4.x * 121 + lab1[jj] * 11 + lab1[i]], 1); }
                { int n = n0 + 1, i = n / 79, jj = n - i * 79;
                  atomicAdd(&hp[a4.y * 121 + lab1[jj] * 11 + lab1[i]], 1); }
                { int n = n0 + 2, i = n / 79, jj = n - i * 79;
                  atomicAdd(&hp[a4.z * 121 + lab1[jj] * 11 + lab1[i]], 1); }
                { int n = n0 + 3, i = n / 79, jj = n - i * 79;
                  atomicAdd(&hp[a4.w * 121 + lab1[jj] * 11 + lab1[i]], 1); }
            }
        }
        if (t == 64) {   // tail element n=6240 -> i=j=78
            int a = Ag1[6240];
            atomicAdd(&hp[a * 121 + lab1[78] * 11 + lab1[78]], 1);
        }
    } else {
        // graph-2 interior histogram: M2[b][lab2[k]][lab2[l]]  (waves 5-7)
        int* hp = h2[t & 7];
        const int q = t - 320;
        #pragma unroll
        for (int itr = 0; itr < 9; ++itr) {
            int m = q + itr * 192;
            if (m < 1560) {
                int4 a4 = ((const int4*)Ag2)[m];
                int n0 = 4 * m;
                { int n = n0 + 0, k = n / 79, ll = n - k * 79;
                  atomicAdd(&hp[a4.x * 121 + lab2[k] * 11 + lab2[ll]], 1); }
                { int n = n0 + 1, k = n / 79, ll = n - k * 79;
                  atomicAdd(&hp[a4.y * 121 + lab2[k] * 11 + lab2[ll]], 1); }
                { int n = n0 + 2, k = n / 79, ll = n - k * 79;
                  atomicAdd(&hp[a4.z * 121 + lab2[k] * 11 + lab2[ll]], 1); }
                { int n = n0 + 3, k = n / 79, ll = n - k * 79;
                  atomicAdd(&hp[a4.w * 121 + lab2[k] * 11 + lab2[ll]], 1); }
            }
        }
        if (t == 320) {  // tail element n=6240 -> k=l=78
            int b = Ag2[6240];
            atomicAdd(&hp[b * 121 + lab2[78] * 11 + lab2[78]], 1);
        }
    }
    __syncthreads();

    // ---------------- B: reduce histogram copies; build V ----------------
    for (int i = t; i < 605; i += 512) {
        int s1v = 0, s2v = 0;
        #pragma unroll
        for (int w = 0; w < 8; ++w) { s1v += h1[w][i]; s2v += h2[w][i]; }
        M1f[i] = (float)s1v;
        M2f[i] = (float)s2v;
    }
    if (t < 55) { N1f[t] = (float)nd1[t]; N2f[t] = (float)nd2[t]; }
    if (t >= 64 && t < 185) {
        int q = t - 64;
        Vm[q] = rho[q / 11] * E_ext[q] * gam[q % 11];
    }
    __syncthreads();

    // ---------------- C: Ub[b][S][R] = sum_T M2[b][S][T] * V[R][T] -------
    for (int idx = t; idx < 605; idx += 512) {
        int b = idx / 121, r = idx - b * 121;
        int S = r / 11, R = r - S * 11;
        const float* m2 = &M2f[b * 121 + S * 11];
        const float* vr = &Vm[R * 11];
        float s = 0.f;
        #pragma unroll
        for (int T = 0; T < 11; ++T) s = fmaf(m2[T], vr[T], s);
        Ub[idx] = s;
    }
    __syncthreads();

    // ---------------- D: Yb[b][P][R] = sum_S V[P][S] * Ub[b][S][R] -------
    for (int idx = t; idx < 605; idx += 512) {
        int b = idx / 121, r = idx - b * 121;
        int P = r / 11, R = r - P * 11;
        float s = 0.f;
        #pragma unroll
        for (int S = 0; S < 11; ++S) s = fmaf(Vm[P * 11 + S], Ub[b * 121 + S * 11 + R], s);
        Yb[idx] = s;
    }
    __syncthreads();

    // ---------------- E: final contraction + reduce ----------------------
    float part = 0.f;
    if (t < 121) {
        int P = t / 11, R = t - P * 11;
        float qf = 0.f;
        #pragma unroll
        for (int a = 0; a < 5; ++a) {
            float sa = 0.f;
            #pragma unroll
            for (int b = 0; b < 5; ++b) sa = fmaf(T5[a * 5 + b], Yb[b * 121 + t], sa);
            qf = fmaf(M1f[a * 121 + t], sa, qf);
        }
        float sd = 0.f;
        #pragma unroll
        for (int a = 0; a < 5; ++a) {
            float sb = 0.f;
            #pragma unroll
            for (int b = 0; b < 5; ++b) sb = fmaf(T5[a * 5 + b], N2f[b * 11 + R], sb);
            sd = fmaf(N1f[a * 11 + P], sb, sd);
        }
        float vv = Vm[t];
        float dpart = vv * vv * sd;
        float cvp = (float)cnt1[P] * (float)cnt2[R] * Cc[t] * vv;
        part = cvp + 0.5f * (qf - dpart);
    }
    #pragma unroll
    for (int off = 1; off < 64; off <<= 1) part += __shfl_xor(part, off, 64);
    if ((t & 63) == 0) redL[t >> 6] = part;
    __syncthreads();
    if (t == 0) {
        float s = 0.f;
        #pragma unroll
        for (int w = 0; w < 8; ++w) s += redL[w];
        dout[0] = s;
    }
}

extern "C" void kernel_launch(void* const* d_in, const int* in_sizes, int n_in,
                              void* d_out, int out_size, void* d_ws, size_t ws_size,
                              hipStream_t stream) {
    const int*   Ag1 = (const int*)d_in[0];
    const int*   Ag2 = (const int*)d_in[1];
    const int*   l1  = (const int*)d_in[2];
    const int*   l2  = (const int*)d_in[3];
    const float* nw  = (const float*)d_in[4];
    const float* ew  = (const float*)d_in[5];
    float* out = (float*)d_out;

    k_ged<<<1, 512, 0, stream>>>(Ag1, Ag2, l1, l2, nw, ew, out);
}

// Round 10
// 11.676 us; speedup vs baseline: 1.5755x; 1.0129x over previous
//
#include <hip/hip_runtime.h>
#include <hip/hip_bf16.h>

// Problem constants (from reference)
#define NL 10            // node label alphabet
#define NE 4             // edge label alphabet
#define N1 79
#define PAD 10           // pad pseudo-label index
#define NLP 11           // NL + pad
#define NODE_INS_DEL 0.03f
#define SINK_ITERS 10

// ---------------------------------------------------------------------------
// Label-space GED (round-5 derivation). Round-9 structure (11.83us) with ONE
// change: the two interior histogram streams are merged into a single
// balanced loop over all 448 histogram threads (3120 int4 groups, 7 iters of
// stride 448 -> 28 atomics/thread on EVERY wave; round 9 had 36 on g2's
// waves). Per-lane pointer selects, no divergent double-execution.
// All arithmetic (Sinkhorn, B/C/D/E, float order) identical to round 9.
// ---------------------------------------------------------------------------
__global__ __launch_bounds__(512) void k_ged(
    const int* __restrict__ Ag1, const int* __restrict__ Ag2,
    const int* __restrict__ l1, const int* __restrict__ l2,
    const float* __restrict__ nw, const float* __restrict__ ew,
    float* __restrict__ dout)
{
    __shared__ float E_ext[121];        // exp(-0.5*cost) in label space (symmetric)
    __shared__ float Cc[121];           // node-cost in label space (with pad borders)
    __shared__ float T5[25];            // edge-pair cost table
    __shared__ float Vm[121];           // V = diag(rho) E_ext diag(gam)
    __shared__ int   lab1[N1], lab2[N1];
    __shared__ int   cnt1[NLP], cnt2[NLP];
    __shared__ __align__(16) int h1[8][605], h2[8][605];   // privatized histograms
    __shared__ int   nd1[55], nd2[55];         // diagonal histograms [a][P]
    __shared__ float M1f[605], M2f[605];
    __shared__ float N1f[55], N2f[55];
    __shared__ float rho[NLP], gam[NLP];
    __shared__ float Ub[605], Yb[605];
    __shared__ float redL[8];

    const int t = threadIdx.x;

    // ---------------- A0: zero (int4), load labels, build tables ----------
    {
        int4* hz1 = (int4*)&h1[0][0];   // 8*605 = 4840 ints = 1210 int4
        int4* hz2 = (int4*)&h2[0][0];
        const int4 z4 = make_int4(0, 0, 0, 0);
        for (int i = t; i < 1210; i += 512) { hz1[i] = z4; hz2[i] = z4; }
    }
    if (t < 55)  nd1[t] = 0;
    if (t >= 55 && t < 110) nd2[t - 55] = 0;
    if (t >= 158 && t < 168) cnt1[t - 158] = 0;
    if (t >= 168 && t < 178) cnt2[t - 168] = 0;
    if (t == 178) cnt1[PAD] = 1;
    if (t == 179) cnt2[PAD] = 1;
    if (t < N1)               lab1[t] = l1[t];
    if (t >= 79 && t < 158)   lab2[t - 79] = l2[t - 79];
    if (t >= 192 && t < 313) {          // E_ext + Cc (label space, incl pad)
        int q = t - 192, P = q / 11, S = q - P * 11;
        float cost;
        if (P < NL && S < NL) {
            if (P == S) cost = 0.f;
            else {
                int x = min(P, S), y = max(P, S);
                int pidx = x * (NL - 1) - x * (x - 1) / 2 + (y - x - 1);
                cost = fmaxf(nw[pidx], 0.f);
            }
        } else if (P == PAD && S == PAD) cost = 0.f;
        else cost = NODE_INS_DEL;
        Cc[q] = cost;
        E_ext[q] = __expf(-0.5f * cost);
    }
    if (t >= 320 && t < 345) {          // edge table 5x5
        int q = t - 320, a = q / 5, b = q - a * 5;
        float val;
        if (a == 0 && b == 0)       val = 0.f;
        else if (a == 0 || b == 0)  val = fmaxf(ew[NE * (NE - 1) / 2], 0.f);
        else if (a == b)            val = 0.f;
        else {
            int x = min(a, b) - 1, y = max(a, b) - 1;
            int p = x * (NE - 1) - x * (x - 1) / 2 + (y - x - 1);
            val = fmaxf(ew[p], 0.f);
        }
        T5[q] = val;
    }
    __syncthreads();

    // ---------------- A1: label counts ----------------
    if (t < N1)               atomicAdd(&cnt1[lab1[t]], 1);
    if (t >= 79 && t < 158)   atomicAdd(&cnt2[lab2[t - 79]], 1);
    __syncthreads();

    // ---------------- A2: Sinkhorn (wave 0) || histograms (waves 1-7) ----
    if (t < 64) {
        // Label-space Sinkhorn: lane = X*4+q; group of 4 lanes computes the
        // 11-term dot for label X (3 terms per lane), xor-reduced in-group.
        const int X = t >> 2, q = t & 3;
        const bool valid = (X < NLP);
        float ec2[3], ec1[3];
        #pragma unroll
        for (int k = 0; k < 3; ++k) {
            int M = 3 * q + k;
            if (valid && M < NLP) {
                float e = E_ext[X * 11 + M];
                ec2[k] = e * (float)cnt2[M];
                ec1[k] = e * (float)cnt1[M];
            } else { ec2[k] = 0.f; ec1[k] = 0.f; }
        }
        const int s0 = 4 * (3 * q + 0);
        const int s1 = 4 * (3 * q + 1);
        const int s2 = (3 * q + 2 < NLP) ? 4 * (3 * q + 2) : 0;  // clamp: weight is 0
        float gX = 1.0f, rX = 1.0f;
        for (int it = 0; it < SINK_ITERS; ++it) {
            float g0 = __shfl(gX, s0, 64);
            float g1 = __shfl(gX, s1, 64);
            float g2 = __shfl(gX, s2, 64);
            float y = ec2[0] * g0 + ec2[1] * g1 + ec2[2] * g2;
            y += __shfl_xor(y, 1, 64);
            y += __shfl_xor(y, 2, 64);
            rX = valid ? (1.0f / y) : 0.f;
            float r0 = __shfl(rX, s0, 64);
            float r1 = __shfl(rX, s1, 64);
            float r2 = __shfl(rX, s2, 64);
            float z = ec1[0] * r0 + ec1[1] * r1 + ec1[2] * r2;
            z += __shfl_xor(z, 1, 64);
            z += __shfl_xor(z, 2, 64);
            gX = valid ? (1.0f / z) : 0.f;
        }
        if (valid && q == 0) { rho[X] = rX; gam[X] = gX; }
    } else {
        // merged balanced interior histograms (waves 1-7, 448 workers)
        const int cp = t & 7;
        int* hp1 = h1[cp];
        int* hp2 = h2[cp];
        // pad borders (i=79 row / j=79 col of the padded 80x80):
        if (t >= 64 && t < 75)   atomicAdd(&h1[1][(t - 64) * 11 + 10], cnt1[t - 64]);
        if (t >= 80 && t < 90)   atomicAdd(&h1[1][110 + (t - 80)], cnt1[t - 80]);
        if (t >= 96 && t < 107)  atomicAdd(&h2[1][(t - 96) * 11 + 10], cnt2[t - 96]);
        if (t >= 112 && t < 122) atomicAdd(&h2[1][110 + (t - 112)], cnt2[t - 112]);
        // diagonal histograms
        if (t >= 64 && t < 64 + N1) {
            int j = t - 64;
            atomicAdd(&nd1[Ag1[j * 80] * 11 + lab1[j]], 1);   // A1[j][j]
        }
        if (t >= 144 && t < 144 + N1) {
            int k = t - 144;
            atomicAdd(&nd2[Ag2[k * 80] * 11 + lab2[k]], 1);
        }
        if (t == 224) nd1[10] = 1;   // pad diag: a=0, P=PAD
        if (t == 225) nd2[10] = 1;
        // interior stream: 3120 int4 groups (1560/graph), 7 iters stride 448
        const int q = t - 64;
        #pragma unroll
        for (int itr = 0; itr < 7; ++itr) {
            int m = q + itr * 448;
            if (m < 3120) {
                const bool g1f = (m < 1560);
                const int mm = g1f ? m : m - 1560;
                const int*  Asrc = g1f ? Ag1 : Ag2;
                const int*  labs = g1f ? lab1 : lab2;
                int*        hp   = g1f ? hp1 : hp2;
                int4 a4 = ((const int4*)Asrc)[mm];
                int n0 = 4 * mm;
                { int n = n0 + 0, d = n / 79, r = n - d * 79;
                  int fi = g1f ? r : d, se = g1f ? d : r;
                  atomicAdd(&hp[a4.x * 121 + labs[fi] * 11 + labs[se]], 1); }
                { int n = n0 + 1, d = n / 79, r = n - d * 79;
                  int fi = g1f ? r : d, se = g1f ? d : r;
                  atomicAdd(&hp[a4.y * 121 + labs[fi] * 11 + labs[se]], 1); }
                { int n = n0 + 2, d = n / 79, r = n - d * 79;
                  int fi = g1f ? r : d, se = g1f ? d : r;
                  atomicAdd(&hp[a4.z * 121 + labs[fi] * 11 + labs[se]], 1); }
                { int n = n0 + 3, d = n / 79, r = n - d * 79;
                  int fi = g1f ? r : d, se = g1f ? d : r;
                  atomicAdd(&hp[a4.w * 121 + labs[fi] * 11 + labs[se]], 1); }
            }
        }
        if (t == 64) {   // graph-1 tail element n=6240 -> i=j=78
            int a = Ag1[6240];
            atomicAdd(&hp1[a * 121 + lab1[78] * 11 + lab1[78]], 1);
        }
        if (t == 320) {  // graph-2 tail element n=6240 -> k=l=78
            int b = Ag2[6240];
            atomicAdd(&hp2[b * 121 + lab2[78] * 11 + lab2[78]], 1);
        }
    }
    __syncthreads();

    // ---------------- B: reduce histogram copies; build V ----------------
    for (int i = t; i < 605; i += 512) {
        int s1v = 0, s2v = 0;
        #pragma unroll
        for (int w = 0; w < 8; ++w) { s1v += h1[w][i]; s2v += h2[w][i]; }
        M1f[i] = (float)s1v;
        M2f[i] = (float)s2v;
    }
    if (t < 55) { N1f[t] = (float)nd1[t]; N2f[t] = (float)nd2[t]; }
    if (t >= 64 && t < 185) {
        int q = t - 64;
        Vm[q] = rho[q / 11] * E_ext[q] * gam[q % 11];
    }
    __syncthreads();

    // ---------------- C: Ub[b][S][R] = sum_T M2[b][S][T] * V[R][T] -------
    for (int idx = t; idx < 605; idx += 512) {
        int b = idx / 121, r = idx - b * 121;
        int S = r / 11, R = r - S * 11;
        const float* m2 = &M2f[b * 121 + S * 11];
        const float* vr = &Vm[R * 11];
        float s = 0.f;
        #pragma unroll
        for (int T = 0; T < 11; ++T) s = fmaf(m2[T], vr[T], s);
        Ub[idx] = s;
    }
    __syncthreads();

    // ---------------- D: Yb[b][P][R] = sum_S V[P][S] * Ub[b][S][R] -------
    for (int idx = t; idx < 605; idx += 512) {
        int b = idx / 121, r = idx - b * 121;
        int P = r / 11, R = r - P * 11;
        float s = 0.f;
        #pragma unroll
        for (int S = 0; S < 11; ++S) s = fmaf(Vm[P * 11 + S], Ub[b * 121 + S * 11 + R], s);
        Yb[idx] = s;
    }
    __syncthreads();

    // ---------------- E: final contraction + reduce ----------------------
    float part = 0.f;
    if (t < 121) {
        int P = t / 11, R = t - P * 11;
        float qf = 0.f;
        #pragma unroll
        for (int a = 0; a < 5; ++a) {
            float sa = 0.f;
            #pragma unroll
            for (int b = 0; b < 5; ++b) sa = fmaf(T5[a * 5 + b], Yb[b * 121 + t], sa);
            qf = fmaf(M1f[a * 121 + t], sa, qf);
        }
        float sd = 0.f;
        #pragma unroll
        for (int a = 0; a < 5; ++a) {
            float sb = 0.f;
            #pragma unroll
            for (int b = 0; b < 5; ++b) sb = fmaf(T5[a * 5 + b], N2f[b * 11 + R], sb);
            sd = fmaf(N1f[a * 11 + P], sb, sd);
        }
        float vv = Vm[t];
        float dpart = vv * vv * sd;
        float cvp = (float)cnt1[P] * (float)cnt2[R] * Cc[t] * vv;
        part = cvp + 0.5f * (qf - dpart);
    }
    #pragma unroll
    for (int off = 1; off < 64; off <<= 1) part += __shfl_xor(part, off, 64);
    if ((t & 63) == 0) redL[t >> 6] = part;
    __syncthreads();
    if (t == 0) {
        float s = 0.f;
        #pragma unroll
        for (int w = 0; w < 8; ++w) s += redL[w];
        dout[0] = s;
    }
}

extern "C" void kernel_launch(void* const* d_in, const int* in_sizes, int n_in,
                              void* d_out, int out_size, void* d_ws, size_t ws_size,
                              hipStream_t stream) {
    const int*   Ag1 = (const int*)d_in[0];
    const int*   Ag2 = (const int*)d_in[1];
    const int*   l1  = (const int*)d_in[2];
    const int*   l2  = (const int*)d_in[3];
    const float* nw  = (const float*)d_in[4];
    const float* ew  = (const float*)d_in[5];
    float* out = (float*)d_out;

    k_ged<<<1, 512, 0, stream>>>(Ag1, Ag2, l1, l2, nw, ew, out);
}